// Round 7
// baseline (79.048 us; speedup 1.0000x reference)
//
#include <hip/hip_runtime.h>
#include <math.h>

// out[b,c] = tanh( sum_{hw} x[b,c,h,w] * W[c,h,w] + bias[c] )
// x: [B=4096, C=512, 7, 7] f32; each (b,c) row = 49 contiguous floats.
//
// R7 = R5 (best, 74.0 us) with two deltas:
//  1. 128-row tiles / 128-thread blocks: 25088 B LDS -> 6 blocks/CU (was 3)
//     => 6 phase-offset stage/compute streams per CU, smoother HBM demand,
//     half the bytes per barrier drain. Same 12 waves/CU.
//  2. nontemporal output store (write-once; avoid L2 write-allocate churn).
// x staging stays NON-TEMPORAL float4 (R5's +13% lever).

constexpr int K    = 49;    // 7*7
constexpr int ROWS = 128;   // rows per tile == threads per block
constexpr int GRID = 2048;  // %4==0 => c loop-invariant per block

typedef float f32x4 __attribute__((ext_vector_type(4)));

__global__ __launch_bounds__(128) void WGP_84018150245011_kernel(
    const float* __restrict__ x,
    const float* __restrict__ W,
    const float* __restrict__ bias,
    float* __restrict__ out,
    int n_tiles) {
  __shared__ float xs[ROWS * K];  // 25088 B; stride-49 reads -> bank stride 17, conflict-free

  const int tid = threadIdx.x;

  // row = g*128 + tid, c = row % 512 = (g%4)*128 + tid; g%4 == blockIdx.x%4
  // since GRID % 4 == 0 => c loop-invariant.
  const int c = ((blockIdx.x & 3) << 7) | tid;

  float w[K];
  const float* __restrict__ wr = W + c * K;
#pragma unroll
  for (int k = 0; k < K; ++k) w[k] = wr[k];
  const float bi = bias[c];

  for (int g = blockIdx.x; g < n_tiles; g += GRID) {
    // ---- Stage: 1568 float4, block-contiguous, 16B-aligned, NON-TEMPORAL ----
    const f32x4* __restrict__ src4 =
        reinterpret_cast<const f32x4*>(x) + (size_t)g * (ROWS * K / 4);
    f32x4* dst4 = reinterpret_cast<f32x4*>(xs);
#pragma unroll
    for (int j = 0; j < 12; ++j) {          // 12*128 = 1536 float4
      dst4[tid + j * 128] = __builtin_nontemporal_load(&src4[tid + j * 128]);
    }
    if (tid < 32) {                         // remaining 32 float4
      dst4[tid + 1536] = __builtin_nontemporal_load(&src4[tid + 1536]);
    }
    __syncthreads();

    // ---- Reduce: thread t owns row t of this tile ----
    const float* xr = xs + tid * K;
    float s = bi;
#pragma unroll
    for (int k = 0; k < K; ++k) {
      s = fmaf(xr[k], w[k], s);
    }
    __builtin_nontemporal_store(tanhf(s), &out[(size_t)g * ROWS + tid]);
    __syncthreads();  // WAR guard before next tile's stage
  }
}

extern "C" void kernel_launch(void* const* d_in, const int* in_sizes, int n_in,
                              void* d_out, int out_size, void* d_ws, size_t ws_size,
                              hipStream_t stream) {
  const float* x    = (const float*)d_in[0];
  const float* W    = (const float*)d_in[1];
  const float* bias = (const float*)d_in[2];
  float* out        = (float*)d_out;

  const int n_rows  = in_sizes[0] / K;       // B*C = 2,097,152
  const int n_tiles = n_rows / ROWS;         // 16384 (exact)

  WGP_84018150245011_kernel<<<GRID, ROWS, 0, stream>>>(x, W, bias, out, n_tiles);
}

// Round 8
// 71.537 us; speedup vs baseline: 1.1050x; 1.1050x over previous
//
#include <hip/hip_runtime.h>
#include <math.h>

// out[b,c] = tanh( sum_{hw} x[b,c,h,w] * W[c,h,w] + bias[c] )
// x: [B=4096, C=512, 7, 7] f32; each (b,c) row = 49 contiguous floats.
//
// R8 = R5 (best, 74.0 us: 256-thread blocks, 50KB LDS tile, NT float4
// staging) + T14 issue-early/write-late prefetch:
//   iteration: write p[] (tile g) -> LDS; barrier; ISSUE NT loads for tile
//   g+1 into p[]; compute tile g from LDS; barrier; repeat.
// The ~900cy HBM latency of the prefetch is covered by the ~500cy compute
// phase + barrier wait instead of being fully exposed before the LDS write
// (R5 consumed loads immediately after issue).

constexpr int K    = 49;   // 7*7
constexpr int ROWS = 256;  // rows per tile == threads per block
constexpr int GRID = 2048; // EVEN => tile parity (g%2) constant per block

typedef float f32x4 __attribute__((ext_vector_type(4)));

__global__ __launch_bounds__(256) void WGP_84018150245011_kernel(
    const float* __restrict__ x,
    const float* __restrict__ W,
    const float* __restrict__ bias,
    float* __restrict__ out,
    int n_tiles) {
  __shared__ float xs[ROWS * K];  // 50176 B; stride-49 reads -> bank stride 17, conflict-free

  const int tid = threadIdx.x;

  // c = (g%2)*256 + tid, g%2 == blockIdx.x%2 (GRID even) => loop-invariant.
  const int c = ((blockIdx.x & 1) << 8) | tid;

  float w[K];
  const float* __restrict__ wr = W + c * K;
#pragma unroll
  for (int k = 0; k < K; ++k) w[k] = wr[k];
  const float bi = bias[c];

  f32x4* dst4 = reinterpret_cast<f32x4*>(xs);

  // 3136 float4 per tile / 256 threads = 12 each + 64 threads carry one extra.
  f32x4 p[12];
  f32x4 ptail;

  // ---- prologue: issue NT loads for first tile ----
  int g = blockIdx.x;
  {
    const f32x4* __restrict__ src4 =
        reinterpret_cast<const f32x4*>(x) + (size_t)g * (ROWS * K / 4);
#pragma unroll
    for (int j = 0; j < 12; ++j) p[j] = __builtin_nontemporal_load(&src4[tid + j * 256]);
    if (tid < 64) ptail = __builtin_nontemporal_load(&src4[tid + 3072]);
  }

#pragma unroll 1
  for (;;) {
    // ---- write p (tile g) to LDS; compiler waits the counted vmcnt here ----
#pragma unroll
    for (int j = 0; j < 12; ++j) dst4[tid + j * 256] = p[j];
    if (tid < 64) dst4[tid + 3072] = ptail;
    __syncthreads();

    const int gn = g + GRID;
    const bool more = (gn < n_tiles);

    // ---- issue-early: NT loads for tile g+1 (consumed only next iteration) ----
    if (more) {
      const f32x4* __restrict__ src4 =
          reinterpret_cast<const f32x4*>(x) + (size_t)gn * (ROWS * K / 4);
#pragma unroll
      for (int j = 0; j < 12; ++j) p[j] = __builtin_nontemporal_load(&src4[tid + j * 256]);
      if (tid < 64) ptail = __builtin_nontemporal_load(&src4[tid + 3072]);
    }

    // ---- compute tile g from LDS (covers the prefetch latency) ----
    {
      const float* xr = xs + tid * K;
      float s = bi;
#pragma unroll
      for (int k = 0; k < K; ++k) s = fmaf(xr[k], w[k], s);
      out[(size_t)g * ROWS + tid] = tanhf(s);
    }
    __syncthreads();  // WAR guard before next write phase

    if (!more) break;
    g = gn;
  }
}

extern "C" void kernel_launch(void* const* d_in, const int* in_sizes, int n_in,
                              void* d_out, int out_size, void* d_ws, size_t ws_size,
                              hipStream_t stream) {
  const float* x    = (const float*)d_in[0];
  const float* W    = (const float*)d_in[1];
  const float* bias = (const float*)d_in[2];
  float* out        = (float*)d_out;

  const int n_rows  = in_sizes[0] / K;       // B*C = 2,097,152
  const int n_tiles = n_rows / ROWS;         // 8192 (exact)

  WGP_84018150245011_kernel<<<GRID, ROWS, 0, stream>>>(x, W, bias, out, n_tiles);
}

// Round 9
// 70.284 us; speedup vs baseline: 1.1247x; 1.0178x over previous
//
#include <hip/hip_runtime.h>
#include <math.h>

// out[b,c] = tanh( sum_{hw} x[b,c,h,w] * W[c,h,w] + bias[c] )
// x: [B=4096, C=512, 7, 7] f32; each (b,c) row = 49 contiguous floats.
//
// R9: ZERO-BARRIER wave-private pipeline. Merges all proven wins:
//  - NT register loads (R5: +13%; R6 showed DMA aux-NT is NOT honored)
//  - issue-early / write-late depth-1 prefetch (R8: +3.4%)
//  - 256-thread blocks, 50 KB LDS, 3 blocks/CU = 12 waves/CU
//  - NEW: each wave owns a private 12.5 KB LDS quarter (its 64 rows) =>
//    no cross-wave dependency => no __syncthreads at all. Same-wave DS
//    ops are FIFO-ordered, so write->read / read->overwrite hazards within
//    a wave are safe; compiler inserts the lgkmcnt/vmcnt register waits.
//  - NT output store (write-once).

constexpr int K    = 49;   // 7*7
constexpr int ROWS = 256;  // rows per block tile (64 per wave)
constexpr int GRID = 2048; // EVEN => channel c loop-invariant per block

typedef float f32x4 __attribute__((ext_vector_type(4)));

__global__ __launch_bounds__(256) void WGP_84018150245011_kernel(
    const float* __restrict__ x,
    const float* __restrict__ W,
    const float* __restrict__ bias,
    float* __restrict__ out,
    int n_tiles) {
  __shared__ float xs[ROWS * K];  // 50176 B; per-wave quarters of 3136 floats

  const int tid  = threadIdx.x;
  const int wave = tid >> 6;
  const int lane = tid & 63;

  // row = g*256 + tid, c = row % 512 = ((g&1)<<8)|tid; g&1 == blockIdx.x&1.
  const int c = ((blockIdx.x & 1) << 8) | tid;

  float w[K];
  const float* __restrict__ wr = W + c * K;
#pragma unroll
  for (int k = 0; k < K; ++k) w[k] = wr[k];
  const float bi = bias[c];

  // Wave-private LDS quarter: rows [64*wave, 64*wave+64) of the tile.
  float* myq  = xs + wave * (64 * K);           // 3136 floats = 784 float4
  f32x4* dst4 = reinterpret_cast<f32x4*>(myq);
  const float* xr = myq + lane * K;             // stride 49 -> bank stride 17, conflict-free

  // Per-wave stage: 784 float4 / 64 lanes = 12 each + lanes 0-15 one extra.
  f32x4 p[12];
  f32x4 ptail;

  auto issue = [&](int g) {
    const f32x4* __restrict__ src4 =
        reinterpret_cast<const f32x4*>(x) + (size_t)g * (ROWS * K / 4) + wave * 784;
#pragma unroll
    for (int j = 0; j < 12; ++j) p[j] = __builtin_nontemporal_load(&src4[lane + j * 64]);
    if (lane < 16) ptail = __builtin_nontemporal_load(&src4[768 + lane]);
  };

  int g = blockIdx.x;
  issue(g);  // prologue

#pragma unroll 1
  for (;;) {
    // ---- write p (tile g) into private quarter; compiler waits counted vmcnt ----
#pragma unroll
    for (int j = 0; j < 12; ++j) dst4[lane + j * 64] = p[j];
    if (lane < 16) dst4[768 + lane] = ptail;

    const int gn = g + GRID;
    const bool more = (gn < n_tiles);

    // ---- issue-early: NT loads for tile g+1 (consumed at next iter's write) ----
    if (more) issue(gn);

    // ---- compute tile g from private quarter (DS FIFO orders after writes) ----
    float s = bi;
#pragma unroll
    for (int k = 0; k < K; ++k) s = fmaf(xr[k], w[k], s);
    __builtin_nontemporal_store(tanhf(s), &out[(size_t)g * ROWS + tid]);

    if (!more) break;
    g = gn;
  }
}

extern "C" void kernel_launch(void* const* d_in, const int* in_sizes, int n_in,
                              void* d_out, int out_size, void* d_ws, size_t ws_size,
                              hipStream_t stream) {
  const float* x    = (const float*)d_in[0];
  const float* W    = (const float*)d_in[1];
  const float* bias = (const float*)d_in[2];
  float* out        = (float*)d_out;

  const int n_rows  = in_sizes[0] / K;       // B*C = 2,097,152
  const int n_tiles = n_rows / ROWS;         // 8192 (exact)

  WGP_84018150245011_kernel<<<GRID, ROWS, 0, stream>>>(x, W, bias, out, n_tiles);
}